// Round 1
// baseline (101.624 us; speedup 1.0000x reference)
//
#include <hip/hip_runtime.h>
#include <hip/hip_bf16.h>
#include <cstdint>
#include <cstddef>

// Problem constants (from reference): T=131072, C=512, O=512, N=1024
#define CC 512
#define OO 512
#define NN 1024
#define CHUNK 16

// ---------------------------------------------------------------------------
// K1: segment boundaries. segment_ids is sorted ascending in [0, N).
// seg_start[n] = first t with sid[t] >= n ; seg_start[N] = T.
// Segment n occupies [seg_start[n], seg_start[n+1]).
// ---------------------------------------------------------------------------
__global__ void seg_bounds_kernel(const int* __restrict__ sid,
                                  int* __restrict__ seg_start,
                                  int T, int N) {
    int t = blockIdx.x * blockDim.x + threadIdx.x;
    if (t >= T) return;
    int s  = sid[t];
    int sp = (t == 0) ? -1 : sid[t - 1];
    for (int n = sp + 1; n <= s; ++n) seg_start[n] = t;
    if (t == T - 1) {
        for (int n = s + 1; n <= N; ++n) seg_start[n] = T;
    }
}

// ---------------------------------------------------------------------------
// K2: per-segment fused score + online softmax + weighted pooling.
// One block (256 threads) per segment. Single pass over x.
// Each thread owns channels [2*tid, 2*tid+1] (float2). y[n] = sum_t w_t x_t.
// ---------------------------------------------------------------------------
__global__ __launch_bounds__(256) void seg_pool_kernel(
    const float* __restrict__ x,       // [T][C]
    const float* __restrict__ wsv_g,   // [C]
    const float* __restrict__ bs_g,    // [1]
    const int*   __restrict__ seg_start,
    float*       __restrict__ y)       // [N][C]
{
    const int n   = blockIdx.x;
    const int s   = seg_start[n];
    const int e   = seg_start[n + 1];
    const int tid = threadIdx.x;
    const int lane = tid & 63;
    const int wv   = tid >> 6;

    const float2 wsv = *reinterpret_cast<const float2*>(wsv_g + 2 * tid);
    const float  bsv = bs_g[0];

    __shared__ float part[CHUNK][4];

    float m = -INFINITY;   // running max (block-uniform)
    float l = 0.f;         // running denominator (block-uniform)
    float ax = 0.f, ay = 0.f;  // weighted accumulators for my 2 channels

    for (int t0 = s; t0 < e; t0 += CHUNK) {
        const int cnt = min(CHUNK, e - t0);

        // --- load chunk rows (coalesced float2 per thread per row) ---
        float2 xr[CHUNK];
        #pragma unroll
        for (int j = 0; j < CHUNK; ++j) {
            if (j < cnt)
                xr[j] = *reinterpret_cast<const float2*>(
                            x + (size_t)(t0 + j) * CC + 2 * tid);
            else
                xr[j] = make_float2(0.f, 0.f);
        }

        // --- per-row score partials + wave butterfly reduce ---
        float p[CHUNK];
        #pragma unroll
        for (int j = 0; j < CHUNK; ++j) {
            p[j] = xr[j].x * wsv.x + xr[j].y * wsv.y;
            #pragma unroll
            for (int off = 32; off >= 1; off >>= 1)
                p[j] += __shfl_xor(p[j], off, 64);
        }
        if (lane == 0) {
            #pragma unroll
            for (int j = 0; j < CHUNK; ++j) part[j][wv] = p[j];
        }
        __syncthreads();

        // --- block-uniform scores + chunk max ---
        float sc[CHUNK];
        float mc = -INFINITY;
        #pragma unroll
        for (int j = 0; j < CHUNK; ++j) {
            sc[j] = part[j][0] + part[j][1] + part[j][2] + part[j][3] + bsv;
            if (j < cnt) mc = fmaxf(mc, sc[j]);
        }
        __syncthreads();  // part[] consumed; safe to overwrite next chunk

        // --- online softmax update ---
        const float newm  = fmaxf(m, mc);
        const float scale = (m == -INFINITY) ? 0.f : __expf(m - newm);
        l  *= scale;
        ax *= scale;
        ay *= scale;
        #pragma unroll
        for (int j = 0; j < CHUNK; ++j) {
            if (j < cnt) {
                const float wj = __expf(sc[j] - newm);
                l  += wj;
                ax += wj * xr[j].x;
                ay += wj * xr[j].y;
            }
        }
        m = newm;
    }

    const float inv = (e > s) ? (1.f / l) : 0.f;
    float2 o;
    o.x = ax * inv;
    o.y = ay * inv;
    *reinterpret_cast<float2*>(y + (size_t)n * CC + 2 * tid) = o;
}

// ---------------------------------------------------------------------------
// K3: out = y @ Wp + bp (in-place on d_out: d_out holds y[N][C] on entry).
// Each block owns 4 rows (reads them fully into LDS before overwriting),
// 256 threads each compute 2 output columns. Empty segments: no bias (=> 0).
// ---------------------------------------------------------------------------
__global__ __launch_bounds__(256) void proj_kernel(
    float*       __restrict__ out,       // [N][O], holds y on entry
    const float* __restrict__ Wp,        // [C][O]
    const float* __restrict__ bp,        // [O]
    const int*   __restrict__ seg_start)
{
    const int n0  = blockIdx.x * 4;
    const int tid = threadIdx.x;

    __shared__ float ylds[4][CC];
    {
        const float* src = out + (size_t)n0 * CC;
        for (int idx = tid; idx < 4 * CC / 4; idx += 256)
            reinterpret_cast<float4*>(&ylds[0][0])[idx] =
                reinterpret_cast<const float4*>(src)[idx];
    }
    __syncthreads();

    const int o0 = tid;
    const int o1 = tid + 256;
    float acc[4][2] = {};

    for (int k = 0; k < CC; k += 4) {
        float4 yv[4];
        #pragma unroll
        for (int r = 0; r < 4; ++r)
            yv[r] = *reinterpret_cast<const float4*>(&ylds[r][k]);
        #pragma unroll
        for (int kk = 0; kk < 4; ++kk) {
            const float w0 = Wp[(size_t)(k + kk) * OO + o0];
            const float w1 = Wp[(size_t)(k + kk) * OO + o1];
            #pragma unroll
            for (int r = 0; r < 4; ++r) {
                const float yval = reinterpret_cast<const float*>(&yv[r])[kk];
                acc[r][0] += yval * w0;
                acc[r][1] += yval * w1;
            }
        }
    }

    #pragma unroll
    for (int r = 0; r < 4; ++r) {
        const int n = n0 + r;
        const bool nonempty = seg_start[n + 1] > seg_start[n];
        const float b0 = nonempty ? bp[o0] : 0.f;
        const float b1 = nonempty ? bp[o1] : 0.f;
        out[(size_t)n * OO + o0] = acc[r][0] + b0;
        out[(size_t)n * OO + o1] = acc[r][1] + b1;
    }
}

// ---------------------------------------------------------------------------
extern "C" void kernel_launch(void* const* d_in, const int* in_sizes, int n_in,
                              void* d_out, int out_size, void* d_ws, size_t ws_size,
                              hipStream_t stream) {
    const float* x    = (const float*)d_in[0];   // [T][C]
    const float* Wp   = (const float*)d_in[1];   // [C][O]
    const float* bp   = (const float*)d_in[2];   // [O]
    const float* wsv  = (const float*)d_in[3];   // [C]
    const float* bs   = (const float*)d_in[4];   // [1]
    const int*   sid  = (const int*)d_in[5];     // [T]
    const int T = in_sizes[5];
    const int N = NN;

    int*   seg_start = (int*)d_ws;               // (N+1) ints
    float* out       = (float*)d_out;            // [N][O]

    seg_bounds_kernel<<<(T + 255) / 256, 256, 0, stream>>>(sid, seg_start, T, N);
    seg_pool_kernel<<<N, 256, 0, stream>>>(x, wsv, bs, seg_start, out);
    proj_kernel<<<N / 4, 256, 0, stream>>>(out, Wp, bp, seg_start);
}

// Round 2
// 92.045 us; speedup vs baseline: 1.1041x; 1.1041x over previous
//
#include <hip/hip_runtime.h>
#include <hip/hip_bf16.h>
#include <cstdint>
#include <cstddef>

// Problem constants: T=131072, C=512, O=512, N=1024
#define CC 512
#define OO 512
#define NN 1024
#define QPARTS 8   // partial waves per segment
#define TB 4       // tokens per pipeline chunk

// ---------------------------------------------------------------------------
// K1: segment boundaries from sorted segment_ids.
// seg_start[n] = first t with sid[t] >= n ; seg_start[N] = T.
// ---------------------------------------------------------------------------
__global__ void seg_bounds_kernel(const int* __restrict__ sid,
                                  int* __restrict__ seg_start,
                                  int T, int N) {
    int t = blockIdx.x * blockDim.x + threadIdx.x;
    if (t >= T) return;
    int s  = sid[t];
    int sp = (t == 0) ? -1 : sid[t - 1];
    for (int n = sp + 1; n <= s; ++n) seg_start[n] = t;
    if (t == T - 1) {
        for (int n = s + 1; n <= N; ++n) seg_start[n] = T;
    }
}

__device__ __forceinline__ float dot4(const float4 a, const float4 b) {
    return a.x * b.x + a.y * b.y + a.z * b.z + a.w * b.w;
}

// ---------------------------------------------------------------------------
// K2: one 64-lane wave per (segment, part). Barrier-free online softmax
// pooling over the part's token range. Lane owns channels [4*lane,4*lane+4)
// and [256+4*lane, 256+4*lane+4): both load streams fully coalesced (1KB/instr).
// Double-buffered register pipeline: load chunk k+1 while computing chunk k.
// Outputs unnormalized acc + (m, l) per part.
// ---------------------------------------------------------------------------
__global__ __launch_bounds__(64) void seg_pool_partial(
    const float* __restrict__ x,       // [T][CC]
    const float* __restrict__ ws_g,    // [CC]
    const float* __restrict__ bs_g,    // [1]
    const int*   __restrict__ seg_start,
    float*       __restrict__ pacc,    // [N*QPARTS][CC]
    float2*      __restrict__ pml)     // [N*QPARTS] (m, l)
{
    const int g = blockIdx.x;
    const int n = g >> 3;              // / QPARTS
    const int q = g & 7;               // % QPARTS
    const int s = seg_start[n];
    const int e = seg_start[n + 1];
    const int len = e - s;
    const int tb = s + (len * q) / QPARTS;
    const int te = s + (len * (q + 1)) / QPARTS;
    const int lane = threadIdx.x;
    const int c0 = lane * 4;

    const float4 w0 = *reinterpret_cast<const float4*>(ws_g + c0);
    const float4 w1 = *reinterpret_cast<const float4*>(ws_g + 256 + c0);
    const float  bsv = bs_g[0];

    float m = -INFINITY, l = 0.f;
    float4 a0 = make_float4(0.f, 0.f, 0.f, 0.f);
    float4 a1 = make_float4(0.f, 0.f, 0.f, 0.f);

    float4 A0[TB], A1[TB], B0[TB], B1[TB];

    auto LOADF = [&](float4 (&b0)[TB], float4 (&b1)[TB], const int t0) {
        #pragma unroll
        for (int j = 0; j < TB; ++j) {
            const int t = t0 + j;
            if (t < te) {
                const float* p = x + (size_t)t * CC;
                b0[j] = *reinterpret_cast<const float4*>(p + c0);
                b1[j] = *reinterpret_cast<const float4*>(p + 256 + c0);
            } else {
                b0[j] = make_float4(0.f, 0.f, 0.f, 0.f);
                b1[j] = make_float4(0.f, 0.f, 0.f, 0.f);
            }
        }
    };

    auto COMP = [&](float4 (&b0)[TB], float4 (&b1)[TB], const int t0) {
        float sc[TB];
        #pragma unroll
        for (int j = 0; j < TB; ++j) {
            float p = dot4(b0[j], w0) + dot4(b1[j], w1);
            #pragma unroll
            for (int off = 32; off >= 1; off >>= 1)
                p += __shfl_xor(p, off, 64);
            sc[j] = p + bsv;
        }
        float mc = -INFINITY;
        #pragma unroll
        for (int j = 0; j < TB; ++j)
            if (t0 + j < te) mc = fmaxf(mc, sc[j]);
        if (mc > m) {  // rescale only when the running max grows
            const float scale = (m == -INFINITY) ? 0.f : __expf(m - mc);
            l *= scale;
            a0.x *= scale; a0.y *= scale; a0.z *= scale; a0.w *= scale;
            a1.x *= scale; a1.y *= scale; a1.z *= scale; a1.w *= scale;
            m = mc;
        }
        #pragma unroll
        for (int j = 0; j < TB; ++j) {
            if (t0 + j < te) {
                const float wj = __expf(sc[j] - m);
                l += wj;
                a0.x += wj * b0[j].x; a0.y += wj * b0[j].y;
                a0.z += wj * b0[j].z; a0.w += wj * b0[j].w;
                a1.x += wj * b1[j].x; a1.y += wj * b1[j].y;
                a1.z += wj * b1[j].z; a1.w += wj * b1[j].w;
            }
        }
    };

    LOADF(A0, A1, tb);
    for (int t0 = tb; t0 < te; t0 += 2 * TB) {
        LOADF(B0, B1, t0 + TB);
        COMP(A0, A1, t0);
        LOADF(A0, A1, t0 + 2 * TB);
        COMP(B0, B1, t0 + TB);
    }

    float* pa = pacc + (size_t)g * CC;
    *reinterpret_cast<float4*>(pa + c0)       = a0;
    *reinterpret_cast<float4*>(pa + 256 + c0) = a1;
    if (lane == 0) pml[g] = make_float2(m, l);
}

// ---------------------------------------------------------------------------
// K3: merge QPARTS partials per segment -> normalized y[n][CC].
// ---------------------------------------------------------------------------
__global__ __launch_bounds__(64) void seg_combine(
    const float*  __restrict__ pacc,
    const float2* __restrict__ pml,
    float*        __restrict__ y)      // [N][CC]
{
    const int n = blockIdx.x;
    const int lane = threadIdx.x;
    const int c0 = lane * 4;
    float* yp = y + (size_t)n * CC;

    float mq[QPARTS];
    float lq[QPARTS];
    float newm = -INFINITY;
    #pragma unroll
    for (int q = 0; q < QPARTS; ++q) {
        const float2 ml = pml[n * QPARTS + q];
        mq[q] = ml.x; lq[q] = ml.y;
        newm = fmaxf(newm, ml.x);
    }

    float4 o0 = make_float4(0.f, 0.f, 0.f, 0.f);
    float4 o1 = make_float4(0.f, 0.f, 0.f, 0.f);

    if (newm == -INFINITY) {  // empty segment -> zeros
        *reinterpret_cast<float4*>(yp + c0)       = o0;
        *reinterpret_cast<float4*>(yp + 256 + c0) = o1;
        return;
    }

    float L = 0.f;
    #pragma unroll
    for (int q = 0; q < QPARTS; ++q) {
        const float wq = __expf(mq[q] - newm);  // 0 for empty parts
        L += wq * lq[q];
        const float* pa = pacc + (size_t)(n * QPARTS + q) * CC;
        const float4 p0 = *reinterpret_cast<const float4*>(pa + c0);
        const float4 p1 = *reinterpret_cast<const float4*>(pa + 256 + c0);
        o0.x += wq * p0.x; o0.y += wq * p0.y; o0.z += wq * p0.z; o0.w += wq * p0.w;
        o1.x += wq * p1.x; o1.y += wq * p1.y; o1.z += wq * p1.z; o1.w += wq * p1.w;
    }
    const float inv = 1.f / L;
    o0.x *= inv; o0.y *= inv; o0.z *= inv; o0.w *= inv;
    o1.x *= inv; o1.y *= inv; o1.z *= inv; o1.w *= inv;
    *reinterpret_cast<float4*>(yp + c0)       = o0;
    *reinterpret_cast<float4*>(yp + 256 + c0) = o1;
}

// ---------------------------------------------------------------------------
// K4: out = y @ Wp + bp, in-place on d_out (d_out holds y on entry).
// Each block owns 4 rows (stages them in LDS before overwriting).
// Empty segments get no bias (=> exact zeros, matching segment_sum).
// ---------------------------------------------------------------------------
__global__ __launch_bounds__(256) void proj_kernel(
    float*       __restrict__ out,     // [N][OO], holds y on entry
    const float* __restrict__ Wp,      // [CC][OO]
    const float* __restrict__ bp,      // [OO]
    const int*   __restrict__ seg_start)
{
    const int n0  = blockIdx.x * 4;
    const int tid = threadIdx.x;

    __shared__ float ylds[4][CC];
    {
        const float* src = out + (size_t)n0 * CC;
        for (int idx = tid; idx < 4 * CC / 4; idx += 256)
            reinterpret_cast<float4*>(&ylds[0][0])[idx] =
                reinterpret_cast<const float4*>(src)[idx];
    }
    __syncthreads();

    const int o0 = tid;
    const int o1 = tid + 256;
    float acc[4][2] = {};

    for (int k = 0; k < CC; k += 4) {
        float4 yv[4];
        #pragma unroll
        for (int r = 0; r < 4; ++r)
            yv[r] = *reinterpret_cast<const float4*>(&ylds[r][k]);
        #pragma unroll
        for (int kk = 0; kk < 4; ++kk) {
            const float w0 = Wp[(size_t)(k + kk) * OO + o0];
            const float w1 = Wp[(size_t)(k + kk) * OO + o1];
            #pragma unroll
            for (int r = 0; r < 4; ++r) {
                const float yval = reinterpret_cast<const float*>(&yv[r])[kk];
                acc[r][0] += yval * w0;
                acc[r][1] += yval * w1;
            }
        }
    }

    #pragma unroll
    for (int r = 0; r < 4; ++r) {
        const int n = n0 + r;
        const bool nonempty = seg_start[n + 1] > seg_start[n];
        const float b0 = nonempty ? bp[o0] : 0.f;
        const float b1 = nonempty ? bp[o1] : 0.f;
        out[(size_t)n * OO + o0] = acc[r][0] + b0;
        out[(size_t)n * OO + o1] = acc[r][1] + b1;
    }
}

// ---------------------------------------------------------------------------
extern "C" void kernel_launch(void* const* d_in, const int* in_sizes, int n_in,
                              void* d_out, int out_size, void* d_ws, size_t ws_size,
                              hipStream_t stream) {
    const float* x    = (const float*)d_in[0];   // [T][C]
    const float* Wp   = (const float*)d_in[1];   // [C][O]
    const float* bp   = (const float*)d_in[2];   // [O]
    const float* wsv  = (const float*)d_in[3];   // [C]
    const float* bs   = (const float*)d_in[4];   // [1]
    const int*   sid  = (const int*)d_in[5];     // [T]
    const int T = in_sizes[5];
    const int N = NN;

    // workspace layout
    int*    seg_start = (int*)d_ws;                                   // (N+1) ints
    float*  pacc      = (float*)((char*)d_ws + 8192);                 // N*Q*CC floats (16 MB)
    float2* pml       = (float2*)((char*)d_ws + 8192 +
                                  (size_t)N * QPARTS * CC * sizeof(float)); // N*Q float2
    float*  out       = (float*)d_out;                                // [N][O]

    seg_bounds_kernel<<<(T + 255) / 256, 256, 0, stream>>>(sid, seg_start, T, N);
    seg_pool_partial<<<N * QPARTS, 64, 0, stream>>>(x, wsv, bs, seg_start, pacc, pml);
    seg_combine<<<N, 64, 0, stream>>>(pacc, pml, out);
    proj_kernel<<<N / 4, 256, 0, stream>>>(out, Wp, bp, seg_start);
}

// Round 4
// 89.850 us; speedup vs baseline: 1.1310x; 1.0244x over previous
//
#include <hip/hip_runtime.h>
#include <hip/hip_bf16.h>
#include <cstdint>
#include <cstddef>

// Problem constants: T=131072, C=512, O=512, N=1024
#define CC 512
#define OO 512
#define NN 1024
#define QP 4   // partial waves per segment

typedef float f4 __attribute__((ext_vector_type(4)));

// ---------------------------------------------------------------------------
// K1: segment boundaries from sorted segment_ids.
// seg_start[n] = first t with sid[t] >= n ; seg_start[N] = T.
// ---------------------------------------------------------------------------
__global__ void seg_bounds_kernel(const int* __restrict__ sid,
                                  int* __restrict__ seg_start,
                                  int T, int N) {
    int t = blockIdx.x * blockDim.x + threadIdx.x;
    if (t >= T) return;
    int s  = sid[t];
    int sp = (t == 0) ? -1 : sid[t - 1];
    for (int n = sp + 1; n <= s; ++n) seg_start[n] = t;
    if (t == T - 1) {
        for (int n = s + 1; n <= N; ++n) seg_start[n] = T;
    }
}

__device__ __forceinline__ float dot4(const f4 a, const f4 b) {
    return a.x * b.x + a.y * b.y + a.z * b.z + a.w * b.w;
}

__device__ __forceinline__ float wave_sum(float p) {
    #pragma unroll
    for (int off = 32; off >= 1; off >>= 1)
        p += __shfl_xor(p, off, 64);
    return p;
}

// ---------------------------------------------------------------------------
// K2: one 64-lane wave per (segment, quarter). Part boundaries rounded to
// multiples of 8 tokens -> main loop is 100% branch-free (single basic block:
// LOAD4(next) || COMP4(cur)), loads stay in flight across iterations.
// Tail (only in part q=3) handled by <=2 clamped, score-masked chunks.
// Lane owns channels [4L,4L+4) and [256+4L,256+4L+4): every load instruction
// is a fully-coalesced 1KB wave segment. Nontemporal: x is read exactly once.
// ---------------------------------------------------------------------------
__global__ __launch_bounds__(64) void seg_pool_partial(
    const float* __restrict__ x,       // [T][CC]
    const float* __restrict__ ws_g,    // [CC]
    const float* __restrict__ bs_g,    // [1]
    const int*   __restrict__ seg_start,
    float*       __restrict__ pacc,    // [N*QP][CC]
    float2*      __restrict__ pml)     // [N*QP] (m, l)
{
    const int g = blockIdx.x;
    const int n = g >> 2;
    const int q = g & 3;
    const int s = seg_start[n];
    const int e = seg_start[n + 1];
    const int len = e - s;
    const int tb = s + (((len * q) >> 2) & ~7);
    const int te = (q == 3) ? e : (s + (((len * (q + 1)) >> 2) & ~7));
    const int lane = threadIdx.x;
    const int c0 = lane * 4;

    const f4 w0 = *reinterpret_cast<const f4*>(ws_g + c0);
    const f4 w1 = *reinterpret_cast<const f4*>(ws_g + 256 + c0);
    const float bsv = bs_g[0];

    float m = -INFINITY, l = 0.f;
    f4 a0 = {0.f, 0.f, 0.f, 0.f};
    f4 a1 = {0.f, 0.f, 0.f, 0.f};

    const int nTok  = te - tb;
    const int nIter = nTok >> 3;

    f4 A0[4], A1[4], B0[4], B1[4];

    auto LOAD4 = [&](f4 (&b0)[4], f4 (&b1)[4], const float* p) {
        #pragma unroll
        for (int j = 0; j < 4; ++j) {
            const float* r = p + (size_t)j * CC;
            b0[j] = __builtin_nontemporal_load(
                        reinterpret_cast<const f4*>(r + c0));
            b1[j] = __builtin_nontemporal_load(
                        reinterpret_cast<const f4*>(r + 256 + c0));
        }
    };

    auto COMP4 = [&](const f4 (&b0)[4], const f4 (&b1)[4]) {
        float sc[4];
        #pragma unroll
        for (int j = 0; j < 4; ++j)
            sc[j] = wave_sum(dot4(b0[j], w0) + dot4(b1[j], w1)) + bsv;
        const float mc = fmaxf(fmaxf(sc[0], sc[1]), fmaxf(sc[2], sc[3]));
        const float newm  = fmaxf(m, mc);
        const float scale = __expf(m - newm);   // exp(-inf)=0 on first chunk
        m = newm;
        l *= scale;
        a0 *= scale;
        a1 *= scale;
        #pragma unroll
        for (int j = 0; j < 4; ++j) {
            const float wj = __expf(sc[j] - m);
            l += wj;
            a0 += wj * b0[j];
            a1 += wj * b1[j];
        }
    };

    const float* base = x + (size_t)tb * CC;

    if (nIter > 0) {
        LOAD4(A0, A1, base);
        for (int i = 0; i < nIter - 1; ++i) {
            const float* p = base + (size_t)(i * 8) * CC;
            LOAD4(B0, B1, p + 4 * CC);
            COMP4(A0, A1);
            LOAD4(A0, A1, p + 8 * CC);
            COMP4(B0, B1);
        }
        LOAD4(B0, B1, base + (size_t)((nIter - 1) * 8 + 4) * CC);
        COMP4(A0, A1);
        COMP4(B0, B1);
    }

    // clamped + masked remainder (<=2 chunks, only part q=3 ever enters)
    for (int t0 = tb + nIter * 8; t0 < te; t0 += 4) {
        #pragma unroll
        for (int j = 0; j < 4; ++j) {
            int t = t0 + j;
            t = (t < te) ? t : (te - 1);
            const float* r = x + (size_t)t * CC;
            A0[j] = __builtin_nontemporal_load(
                        reinterpret_cast<const f4*>(r + c0));
            A1[j] = __builtin_nontemporal_load(
                        reinterpret_cast<const f4*>(r + 256 + c0));
        }
        float sc[4];
        #pragma unroll
        for (int j = 0; j < 4; ++j) {
            sc[j] = wave_sum(dot4(A0[j], w0) + dot4(A1[j], w1)) + bsv;
            if (t0 + j >= te) sc[j] = -INFINITY;   // uniform select
        }
        const float mc = fmaxf(fmaxf(sc[0], sc[1]), fmaxf(sc[2], sc[3]));
        const float newm  = fmaxf(m, mc);
        const float scale = __expf(m - newm);
        m = newm;
        l *= scale;
        a0 *= scale;
        a1 *= scale;
        #pragma unroll
        for (int j = 0; j < 4; ++j) {
            const float wj = __expf(sc[j] - m);   // 0 for masked tokens
            l += wj;
            a0 += wj * A0[j];
            a1 += wj * A1[j];
        }
    }

    float* pa = pacc + (size_t)g * CC;
    *reinterpret_cast<f4*>(pa + c0)       = a0;
    *reinterpret_cast<f4*>(pa + 256 + c0) = a1;
    if (lane == 0) pml[g] = make_float2(m, l);
}

// ---------------------------------------------------------------------------
// K3: merge QP partials per segment -> normalized y[n][CC] (into d_out).
// ---------------------------------------------------------------------------
__global__ __launch_bounds__(64) void seg_combine(
    const float*  __restrict__ pacc,
    const float2* __restrict__ pml,
    float*        __restrict__ y)      // [N][CC]
{
    const int n = blockIdx.x;
    const int lane = threadIdx.x;
    const int c0 = lane * 4;
    float* yp = y + (size_t)n * CC;

    float mq[QP], lq[QP];
    float newm = -INFINITY;
    #pragma unroll
    for (int q = 0; q < QP; ++q) {
        const float2 ml = pml[n * QP + q];
        mq[q] = ml.x; lq[q] = ml.y;
        newm = fmaxf(newm, ml.x);
    }

    f4 o0 = {0.f, 0.f, 0.f, 0.f};
    f4 o1 = {0.f, 0.f, 0.f, 0.f};

    if (newm == -INFINITY) {  // empty segment -> zeros
        *reinterpret_cast<f4*>(yp + c0)       = o0;
        *reinterpret_cast<f4*>(yp + 256 + c0) = o1;
        return;
    }

    float L = 0.f;
    #pragma unroll
    for (int q = 0; q < QP; ++q) {
        const float wq = __expf(mq[q] - newm);
        L += wq * lq[q];
        const float* pa = pacc + (size_t)(n * QP + q) * CC;
        const f4 p0 = *reinterpret_cast<const f4*>(pa + c0);
        const f4 p1 = *reinterpret_cast<const f4*>(pa + 256 + c0);
        o0 += wq * p0;
        o1 += wq * p1;
    }
    const float inv = 1.f / L;
    o0 *= inv;
    o1 *= inv;
    *reinterpret_cast<f4*>(yp + c0)       = o0;
    *reinterpret_cast<f4*>(yp + 256 + c0) = o1;
}

// ---------------------------------------------------------------------------
// K4: out = y @ Wp + bp, in-place on d_out (d_out holds y on entry).
// Each block owns 4 rows (stages them in LDS before overwriting).
// Empty segments get no bias (=> exact zeros, matching segment_sum).
// ---------------------------------------------------------------------------
__global__ __launch_bounds__(256) void proj_kernel(
    float*       __restrict__ out,     // [N][OO], holds y on entry
    const float* __restrict__ Wp,      // [CC][OO]
    const float* __restrict__ bp,      // [OO]
    const int*   __restrict__ seg_start)
{
    const int n0  = blockIdx.x * 4;
    const int tid = threadIdx.x;

    __shared__ float ylds[4][CC];
    {
        const float* src = out + (size_t)n0 * CC;
        for (int idx = tid; idx < 4 * CC / 4; idx += 256)
            reinterpret_cast<float4*>(&ylds[0][0])[idx] =
                reinterpret_cast<const float4*>(src)[idx];
    }
    __syncthreads();

    const int o0 = tid;
    const int o1 = tid + 256;
    float acc[4][2] = {};

    for (int k = 0; k < CC; k += 4) {
        float4 yv[4];
        #pragma unroll
        for (int r = 0; r < 4; ++r)
            yv[r] = *reinterpret_cast<const float4*>(&ylds[r][k]);
        #pragma unroll
        for (int kk = 0; kk < 4; ++kk) {
            const float w0 = Wp[(size_t)(k + kk) * OO + o0];
            const float w1 = Wp[(size_t)(k + kk) * OO + o1];
            #pragma unroll
            for (int r = 0; r < 4; ++r) {
                const float yval = reinterpret_cast<const float*>(&yv[r])[kk];
                acc[r][0] += yval * w0;
                acc[r][1] += yval * w1;
            }
        }
    }

    #pragma unroll
    for (int r = 0; r < 4; ++r) {
        const int n = n0 + r;
        const bool nonempty = seg_start[n + 1] > seg_start[n];
        const float b0 = nonempty ? bp[o0] : 0.f;
        const float b1 = nonempty ? bp[o1] : 0.f;
        out[(size_t)n * OO + o0] = acc[r][0] + b0;
        out[(size_t)n * OO + o1] = acc[r][1] + b1;
    }
}

// ---------------------------------------------------------------------------
extern "C" void kernel_launch(void* const* d_in, const int* in_sizes, int n_in,
                              void* d_out, int out_size, void* d_ws, size_t ws_size,
                              hipStream_t stream) {
    const float* x    = (const float*)d_in[0];   // [T][C]
    const float* Wp   = (const float*)d_in[1];   // [C][O]
    const float* bp   = (const float*)d_in[2];   // [O]
    const float* wsv  = (const float*)d_in[3];   // [C]
    const float* bs   = (const float*)d_in[4];   // [1]
    const int*   sid  = (const int*)d_in[5];     // [T]
    const int T = in_sizes[5];
    const int N = NN;

    // workspace layout
    int*    seg_start = (int*)d_ws;                                   // (N+1) ints
    float*  pacc      = (float*)((char*)d_ws + 8192);                 // N*QP*CC floats (8 MB)
    float2* pml       = (float2*)((char*)d_ws + 8192 +
                                  (size_t)N * QP * CC * sizeof(float)); // N*QP float2
    float*  out       = (float*)d_out;                                // [N][O]

    seg_bounds_kernel<<<(T + 255) / 256, 256, 0, stream>>>(sid, seg_start, T, N);
    seg_pool_partial<<<N * QP, 64, 0, stream>>>(x, wsv, bs, seg_start, pacc, pml);
    seg_combine<<<N, 64, 0, stream>>>(pacc, pml, out);
    proj_kernel<<<N / 4, 256, 0, stream>>>(out, Wp, bp, seg_start);
}